// Round 8
// baseline (21.830 us; speedup 1.0000x reference)
//
#include <hip/hip_runtime.h>

#define NSAMP 4096
#define SS0 3969   // 63*63
#define SS1 961    // 31*31

typedef float f4v __attribute__((ext_vector_type(4), aligned(4)));

struct Lvl0 { f4v L[4]; int yv[4]; bool dg[4]; };
struct Lvl1 { f4v L; int y1, yc1, g1; bool dg; };

__device__ __forceinline__ void issue_l0(const float* __restrict__ p0, int wid, int lane, Lvl0& o) {
    const int g = lane & 15, r = lane >> 4;
    #pragma unroll
    for (int it = 0; it < 4; ++it) {
        const int yy = 16 * it + 4 * wid + r;        // 0..63 (63 masked later)
        const int yc = (yy > 62) ? 62 : yy;          // clamp keeps load in-bounds
        const bool danger = (yc == 62) & (g == 15);  // would touch elem 3969
        const int e = yc * 63 + 4 * g - (danger ? 1 : 0);
        o.L[it] = *reinterpret_cast<const f4v*>(p0 + e);
        o.yv[it] = yy; o.dg[it] = danger;
    }
}

__device__ __forceinline__ void issue_l1(const float* __restrict__ p1, int wid, int lane, Lvl1& o) {
    o.g1  = lane & 7;
    o.y1  = 8 * wid + (lane >> 3);                   // 0..31 (31 masked later)
    o.yc1 = (o.y1 > 30) ? 30 : o.y1;
    o.dg  = (o.yc1 == 30) & (o.g1 == 7);
    o.L = *reinterpret_cast<const f4v*>(p1 + o.yc1 * 31 + 4 * o.g1 - (o.dg ? 1 : 0));
}

__device__ __forceinline__ void consume_l0(const Lvl0& in, const float* g0x, const float* g0y,
                                           int lane, float& T0, float& A0, float& B0) {
    const int g = lane & 15;
    const float keep3 = (g < 15) ? 1.0f : 0.0f;
    const float gx00 = g0x[4 * g], gx01 = g0x[4 * g + 1];
    const float gx02 = g0x[4 * g + 2], gx03 = g0x[4 * g + 3];
    float T = 0.0f, A = 0.0f, Bc0 = 0.0f, Bc1 = 0.0f, Bc2 = 0.0f, Bc3 = 0.0f;
    #pragma unroll
    for (int it = 0; it < 4; ++it) {
        const float m = (in.yv[it] < 63) ? 1.0f : 0.0f;
        const int  yc = (in.yv[it] > 62) ? 62 : in.yv[it];
        const f4v  v  = in.L[it];
        const bool d  = in.dg[it];
        const float c0 = (d ? v.y : v.x) * m;
        const float c1 = (d ? v.z : v.y) * m;
        const float c2 = (d ? v.w : v.z) * m;
        const float c3 = (d ? 0.0f : v.w) * keep3 * m;
        const float gyv = g0y[yc];
        T += (c0 + c1) + (c2 + c3);
        A = fmaf(c0, c0, A); A = fmaf(c1, c1, A);
        A = fmaf(c2, c2, A); A = fmaf(c3, c3, A);
        Bc0 = fmaf(c0, gyv, Bc0); Bc1 = fmaf(c1, gyv, Bc1);
        Bc2 = fmaf(c2, gyv, Bc2); Bc3 = fmaf(c3, gyv, Bc3);
    }
    T0 = T; A0 = A;
    B0 = (Bc0 * gx00 + Bc1 * gx01) + (Bc2 * gx02 + Bc3 * gx03);
}

__device__ __forceinline__ void consume_l1(const Lvl1& in, const float* g1x, const float* g1y,
                                           float& T1, float& A1, float& B1) {
    const float m1 = (in.y1 < 31) ? 1.0f : 0.0f;
    const float keep3 = (in.g1 < 7) ? 1.0f : 0.0f;
    const f4v v = in.L;
    const float c0 = (in.dg ? v.y : v.x) * m1;
    const float c1 = (in.dg ? v.z : v.y) * m1;
    const float c2 = (in.dg ? v.w : v.z) * m1;
    const float c3 = (in.dg ? 0.0f : v.w) * keep3 * m1;
    const float gyv = g1y[in.yc1];
    const float gx10 = g1x[4 * in.g1],     gx11 = g1x[4 * in.g1 + 1];
    const float gx12 = g1x[4 * in.g1 + 2], gx13 = g1x[4 * in.g1 + 3];
    T1 = (c0 + c1) + (c2 + c3);
    A1 = fmaf(c0, c0, fmaf(c1, c1, fmaf(c2, c2, c3 * c3)));
    B1 = gyv * ((c0 * gx10 + c1 * gx11) + (c2 * gx12 + c3 * gx13));
}

// Builds one Gaussian table (wave wid owns table wid) + square-sum for C.
__device__ __forceinline__ void build_tables(const float4 bb, int wid, int lane,
                                             float* g0x, float* g0y, float* g1x, float* g1y,
                                             float* sg /*[4]*/) {
    const float cx = 0.5f * (bb.x + bb.z) - 64.0f;
    const float cy = 0.5f * (bb.y + bb.w) - 64.0f;
    const float bw = bb.z - bb.x;
    const float bh = bb.w - bb.y;
    const float invs  = (wid < 2) ? 0.25f : 0.125f;
    const bool  horiz = !(wid & 1);
    const int   len   = (wid < 2) ? 63 : 31;
    const int   tsz   = (wid < 2) ? 64 : 32;
    float* tbl = (wid == 0) ? g0x : (wid == 1) ? g0y : (wid == 2) ? g1x : g1y;
    const float mu  = (horiz ? cx : cy) * invs;
    const float is  = 1.0f / (0.2f * (horiz ? bw : bh) * invs);
    const float amp = 0.39894228040143267794f * is;
    float v = 0.0f;
    if (lane < len) {
        float d = ((float)lane - mu) * is;
        v = amp * __expf(-0.5f * d * d);
    }
    if (lane < tsz) tbl[lane] = v;   // zero beyond len
    float v2 = v * v;
    #pragma unroll
    for (int off = 32; off > 0; off >>= 1) v2 += __shfl_down(v2, off);
    if (lane == 0) sg[wid] = v2;
}

// Two samples per block: issue all 10 dwordx4 loads first, build both samples'
// tables under the load latency, then consume A then B.
__global__ __launch_bounds__(256) void heat_main_kernel(
    const float* __restrict__ cls0,
    const float* __restrict__ cls1,
    const float* __restrict__ gt,
    float* __restrict__ partial)      // (NSAMP/2,)
{
    __shared__ float g0xA[64], g0yA[64], g1xA[32], g1yA[32], sgA[4];
    __shared__ float g0xB[64], g0yB[64], g1xB[32], g1yB[32], sgB[4];
    __shared__ float red[4][12];

    const int bid  = blockIdx.x;
    const int sidA = 2 * bid;
    const int sidB = 2 * bid + 1;
    const int tid  = threadIdx.x;
    const int lane = tid & 63;
    const int wid  = tid >> 6;

    // ---- phase 1: issue everything ----
    const float4 bbA = *reinterpret_cast<const float4*>(gt + (size_t)sidA * 4);
    const float4 bbB = *reinterpret_cast<const float4*>(gt + (size_t)sidB * 4);

    Lvl0 l0A, l0B; Lvl1 l1A, l1B;
    issue_l0(cls0 + (size_t)sidA * SS0, wid, lane, l0A);
    issue_l1(cls1 + (size_t)sidA * SS1, wid, lane, l1A);
    issue_l0(cls0 + (size_t)sidB * SS0, wid, lane, l0B);
    issue_l1(cls1 + (size_t)sidB * SS1, wid, lane, l1B);

    // ---- phase 2: tables for both samples (overlaps load latency) ----
    build_tables(bbA, wid, lane, g0xA, g0yA, g1xA, g1yA, sgA);
    build_tables(bbB, wid, lane, g0xB, g0yB, g1xB, g1yB, sgB);
    __syncthreads();

    // ---- phase 3: consume (A first: its loads were issued first) ----
    float T0A, A0A, B0A, T1A, A1A, B1A;
    consume_l0(l0A, g0xA, g0yA, lane, T0A, A0A, B0A);
    consume_l1(l1A, g1xA, g1yA, T1A, A1A, B1A);
    float T0B, A0B, B0B, T1B, A1B, B1B;
    consume_l0(l0B, g0xB, g0yB, lane, T0B, A0B, B0B);
    consume_l1(l1B, g1xB, g1yB, T1B, A1B, B1B);

    // ---- block reduction of 12 partials ----
    #pragma unroll
    for (int off = 32; off > 0; off >>= 1) {
        T0A += __shfl_down(T0A, off); A0A += __shfl_down(A0A, off); B0A += __shfl_down(B0A, off);
        T1A += __shfl_down(T1A, off); A1A += __shfl_down(A1A, off); B1A += __shfl_down(B1A, off);
        T0B += __shfl_down(T0B, off); A0B += __shfl_down(A0B, off); B0B += __shfl_down(B0B, off);
        T1B += __shfl_down(T1B, off); A1B += __shfl_down(A1B, off); B1B += __shfl_down(B1B, off);
    }
    if (lane == 0) {
        red[wid][0] = T0A; red[wid][1]  = A0A; red[wid][2]  = B0A;
        red[wid][3] = T1A; red[wid][4]  = A1A; red[wid][5]  = B1A;
        red[wid][6] = T0B; red[wid][7]  = A0B; red[wid][8]  = B0B;
        red[wid][9] = T1B; red[wid][10] = A1B; red[wid][11] = B1B;
    }
    __syncthreads();
    if (tid == 0) {
        float s[12];
        #pragma unroll
        for (int j = 0; j < 12; ++j)
            s[j] = ((red[0][j] + red[1][j]) + (red[2][j] + red[3][j]));
        const float C0A = sgA[0] * sgA[1], C1A = sgA[2] * sgA[3];
        const float C0B = sgB[0] * sgB[1], C1B = sgB[2] * sgB[3];
        const float i0A = 1.0f / s[0], i1A = 1.0f / s[3];
        const float i0B = 1.0f / s[6], i1B = 1.0f / s[9];
        const float lA = (fmaf(s[1] * i0A, i0A, -2.0f * s[2]  * i0A) + C0A) * (1.0f / 3969.0f)
                       + (fmaf(s[4] * i1A, i1A, -2.0f * s[5]  * i1A) + C1A) * (1.0f / 961.0f);
        const float lB = (fmaf(s[7] * i0B, i0B, -2.0f * s[8]  * i0B) + C0B) * (1.0f / 3969.0f)
                       + (fmaf(s[10] * i1B, i1B, -2.0f * s[11] * i1B) + C1B) * (1.0f / 961.0f);
        partial[bid] = lA + lB;   // fixed order: deterministic
    }
}

// Deterministic fixed-order final reduction of NSAMP/2 = 2048 partials.
__global__ __launch_bounds__(512) void heat_final_kernel(
    const float* __restrict__ partial, float* __restrict__ out)
{
    __shared__ float red[8];
    const int tid = threadIdx.x;
    const float4 v = reinterpret_cast<const float4*>(partial)[tid];  // 512*4 = 2048
    float s = (v.x + v.y) + (v.z + v.w);
    #pragma unroll
    for (int off = 32; off > 0; off >>= 1) s += __shfl_down(s, off);
    if ((tid & 63) == 0) red[tid >> 6] = s;
    __syncthreads();
    if (tid == 0) {
        float t = 0.0f;
        #pragma unroll
        for (int w = 0; w < 8; ++w) t += red[w];
        out[0] = t;
    }
}

extern "C" void kernel_launch(void* const* d_in, const int* in_sizes, int n_in,
                              void* d_out, int out_size, void* d_ws, size_t ws_size,
                              hipStream_t stream) {
    // inputs: 0=cls0 (N,1,63,63), 1=reg0 (unused), 2=cls1 (N,1,31,31),
    //         3=reg1 (unused), 4=gt_bbox (N,4)
    const float* cls0 = (const float*)d_in[0];
    const float* cls1 = (const float*)d_in[2];
    const float* gt   = (const float*)d_in[4];
    float* out = (float*)d_out;
    float* ws  = (float*)d_ws;   // NSAMP/2 floats = 8 KiB

    heat_main_kernel<<<NSAMP / 2, 256, 0, stream>>>(cls0, cls1, gt, ws);
    heat_final_kernel<<<1, 512, 0, stream>>>(ws, out);
}

// Round 9
// 20.796 us; speedup vs baseline: 1.0497x; 1.0497x over previous
//
#include <hip/hip_runtime.h>

#define NSAMP 4096
#define SS0 3969   // 63*63
#define SS1 961    // 31*31

typedef float f4v __attribute__((ext_vector_type(4), aligned(4)));

// Per-sample loss over both pyramid levels, one block per sample.
// loss = sum_levels (A/T^2 - 2B/T + C) / (S*S)
//   T = sum c, A = sum c^2, B = sum c*h, C = (sum gy^2)(sum gx^2)
// Structure: issue ALL global loads up-front; build Gaussian tables under the
// load latency; consume. Register diet: only the 5 f4v payloads are kept live
// across the barrier — row indices / edge flags are recomputed in consume.
// __launch_bounds__(256, 8): force 8 blocks/CU (8 waves/SIMD, VGPR <= 64).
__global__ __launch_bounds__(256, 8) void heat_main_kernel(
    const float* __restrict__ cls0,   // (NSAMP, 63*63)
    const float* __restrict__ cls1,   // (NSAMP, 31*31)
    const float* __restrict__ gt,     // (NSAMP, 4)
    float* __restrict__ partial)      // (NSAMP,)
{
    __shared__ float g0x[64], g0y[64], g1x[32], g1y[32];
    __shared__ float sg[4];    // {sum g0x^2, sum g0y^2, sum g1x^2, sum g1y^2}
    __shared__ float red[4][6];

    const int sid  = blockIdx.x;
    const int tid  = threadIdx.x;
    const int lane = tid & 63;
    const int wid  = tid >> 6;

    // ---------- phase 1: issue all global loads (1 + 4 + 1 per thread) ----------
    const float4 bb = *reinterpret_cast<const float4*>(gt + (size_t)sid * 4);

    const float* __restrict__ p0 = cls0 + (size_t)sid * SS0;
    const float* __restrict__ p1 = cls1 + (size_t)sid * SS1;

    // level 0: wave = 4 rows x 64 cols; lane = (r=lane>>4, g=lane&15)
    const int g = lane & 15;
    const int r = lane >> 4;
    f4v L0[4];
    #pragma unroll
    for (int it = 0; it < 4; ++it) {
        const int yy = 16 * it + 4 * wid + r;        // 0..63 (63 masked in consume)
        const int yc = (yy > 62) ? 62 : yy;          // clamp: load stays in-bounds
        const bool danger = (yc == 62) & (g == 15);  // would touch elem 3969
        const int e = yc * 63 + 4 * g - (danger ? 1 : 0);
        L0[it] = *reinterpret_cast<const f4v*>(p0 + e);
    }
    // level 1: wave = 8 rows x 32 cols
    const int g1  = lane & 7;
    const int y1  = 8 * wid + (lane >> 3);           // 0..31 (31 masked in consume)
    const int yc1 = (y1 > 30) ? 30 : y1;
    const bool dg1 = (yc1 == 30) & (g1 == 7);
    const f4v L1 = *reinterpret_cast<const f4v*>(p1 + yc1 * 31 + 4 * g1 - (dg1 ? 1 : 0));

    // ---------- phase 2: Gaussian tables (overlaps load latency) ----------
    {
        const float cx = 0.5f * (bb.x + bb.z) - 64.0f;
        const float cy = 0.5f * (bb.y + bb.w) - 64.0f;
        const float bw = bb.z - bb.x;
        const float bh = bb.w - bb.y;
        const float invs  = (wid < 2) ? 0.25f : 0.125f;
        const bool  horiz = !(wid & 1);
        const int   len   = (wid < 2) ? 63 : 31;
        const int   tsz   = (wid < 2) ? 64 : 32;
        float* tbl = (wid == 0) ? g0x : (wid == 1) ? g0y : (wid == 2) ? g1x : g1y;
        const float mu  = (horiz ? cx : cy) * invs;
        const float is  = 1.0f / (0.2f * (horiz ? bw : bh) * invs);
        const float amp = 0.39894228040143267794f * is;
        float v = 0.0f;
        if (lane < len) {
            float d = ((float)lane - mu) * is;
            v = amp * __expf(-0.5f * d * d);
        }
        if (lane < tsz) tbl[lane] = v;   // zero beyond len
        float v2 = v * v;
        #pragma unroll
        for (int off = 32; off > 0; off >>= 1) v2 += __shfl_down(v2, off);
        if (lane == 0) sg[wid] = v2;
    }
    __syncthreads();

    // ---------- phase 3: consume (indices recomputed — not kept in VGPRs) ----------
    const float keep3_0 = (g < 15) ? 1.0f : 0.0f;
    const float gx00 = g0x[4 * g], gx01 = g0x[4 * g + 1];
    const float gx02 = g0x[4 * g + 2], gx03 = g0x[4 * g + 3];

    float T0 = 0.0f, A0 = 0.0f;
    float Bc0 = 0.0f, Bc1 = 0.0f, Bc2 = 0.0f, Bc3 = 0.0f;
    #pragma unroll
    for (int it = 0; it < 4; ++it) {
        const int  yy = 16 * it + 4 * wid + r;           // recompute (reg diet)
        const int  yc = (yy > 62) ? 62 : yy;
        const bool d  = (yc == 62) & (g == 15);
        const float m = (yy < 63) ? 1.0f : 0.0f;
        const f4v  v  = L0[it];
        const float c0 = (d ? v.y : v.x) * m;
        const float c1 = (d ? v.z : v.y) * m;
        const float c2 = (d ? v.w : v.z) * m;
        const float c3 = (d ? 0.0f : v.w) * keep3_0 * m;
        const float gyv = g0y[yc];
        T0 += (c0 + c1) + (c2 + c3);
        A0 = fmaf(c0, c0, A0); A0 = fmaf(c1, c1, A0);
        A0 = fmaf(c2, c2, A0); A0 = fmaf(c3, c3, A0);
        Bc0 = fmaf(c0, gyv, Bc0); Bc1 = fmaf(c1, gyv, Bc1);
        Bc2 = fmaf(c2, gyv, Bc2); Bc3 = fmaf(c3, gyv, Bc3);
    }
    float B0 = (Bc0 * gx00 + Bc1 * gx01) + (Bc2 * gx02 + Bc3 * gx03);

    float T1 = 0.0f, A1 = 0.0f, B1 = 0.0f;
    {
        const float m1 = (y1 < 31) ? 1.0f : 0.0f;
        const float keep3_1 = (g1 < 7) ? 1.0f : 0.0f;
        const float c0 = (dg1 ? L1.y : L1.x) * m1;
        const float c1 = (dg1 ? L1.z : L1.y) * m1;
        const float c2 = (dg1 ? L1.w : L1.z) * m1;
        const float c3 = (dg1 ? 0.0f : L1.w) * keep3_1 * m1;
        const float gyv = g1y[yc1];
        const float gx10 = g1x[4 * g1],     gx11 = g1x[4 * g1 + 1];
        const float gx12 = g1x[4 * g1 + 2], gx13 = g1x[4 * g1 + 3];
        T1 = (c0 + c1) + (c2 + c3);
        A1 = fmaf(c0, c0, fmaf(c1, c1, fmaf(c2, c2, c3 * c3)));
        B1 = gyv * ((c0 * gx10 + c1 * gx11) + (c2 * gx12 + c3 * gx13));
    }

    // ---------- block reduction ----------
    #pragma unroll
    for (int off = 32; off > 0; off >>= 1) {
        T0 += __shfl_down(T0, off); A0 += __shfl_down(A0, off); B0 += __shfl_down(B0, off);
        T1 += __shfl_down(T1, off); A1 += __shfl_down(A1, off); B1 += __shfl_down(B1, off);
    }
    if (lane == 0) {
        red[wid][0] = T0; red[wid][1] = A0; red[wid][2] = B0;
        red[wid][3] = T1; red[wid][4] = A1; red[wid][5] = B1;
    }
    __syncthreads();
    if (tid == 0) {
        float t0 = 0, a0 = 0, b0 = 0, t1 = 0, a1 = 0, b1 = 0;
        #pragma unroll
        for (int w = 0; w < 4; ++w) {
            t0 += red[w][0]; a0 += red[w][1]; b0 += red[w][2];
            t1 += red[w][3]; a1 += red[w][4]; b1 += red[w][5];
        }
        const float C0 = sg[0] * sg[1];
        const float C1 = sg[2] * sg[3];
        const float i0 = 1.0f / t0;
        const float i1 = 1.0f / t1;
        const float l0 = (fmaf(a0 * i0, i0, -2.0f * b0 * i0) + C0) * (1.0f / 3969.0f);
        const float l1 = (fmaf(a1 * i1, i1, -2.0f * b1 * i1) + C1) * (1.0f / 961.0f);
        partial[sid] = l0 + l1;
    }
}

// Deterministic fixed-order final reduction of NSAMP partials (float4 loads).
__global__ __launch_bounds__(1024) void heat_final_kernel(
    const float* __restrict__ partial, float* __restrict__ out)
{
    __shared__ float red[16];
    const int tid = threadIdx.x;
    const float4 v = reinterpret_cast<const float4*>(partial)[tid];  // 1024*4 = 4096
    float s = (v.x + v.y) + (v.z + v.w);
    #pragma unroll
    for (int off = 32; off > 0; off >>= 1) s += __shfl_down(s, off);
    if ((tid & 63) == 0) red[tid >> 6] = s;
    __syncthreads();
    if (tid == 0) {
        float t = 0.0f;
        #pragma unroll
        for (int w = 0; w < 16; ++w) t += red[w];
        out[0] = t;
    }
}

extern "C" void kernel_launch(void* const* d_in, const int* in_sizes, int n_in,
                              void* d_out, int out_size, void* d_ws, size_t ws_size,
                              hipStream_t stream) {
    // inputs: 0=cls0 (N,1,63,63), 1=reg0 (unused), 2=cls1 (N,1,31,31),
    //         3=reg1 (unused), 4=gt_bbox (N,4)
    const float* cls0 = (const float*)d_in[0];
    const float* cls1 = (const float*)d_in[2];
    const float* gt   = (const float*)d_in[4];
    float* out = (float*)d_out;
    float* ws  = (float*)d_ws;   // NSAMP floats = 16 KiB

    heat_main_kernel<<<NSAMP, 256, 0, stream>>>(cls0, cls1, gt, ws);
    heat_final_kernel<<<1, 1024, 0, stream>>>(ws, out);
}